// Round 2
// baseline (4370.455 us; speedup 1.0000x reference)
//
#include <hip/hip_runtime.h>
#include <math.h>

#define E 64
#define NOBJ 100000
#define SMOOTH 12.0f
#define KC 32

__device__ __forceinline__ float mish_f(float x) {
    float sp = fmaxf(x, 0.0f) + log1pf(expf(-fabsf(x)));
    return x * tanhf(sp);
}

__device__ __forceinline__ unsigned int enc_f32(float v) {
    int b = __float_as_int(v);
    return (b >= 0) ? ((unsigned int)b | 0x80000000u) : ~((unsigned int)b);
}

// Fused relation-MLP + scatter pass.
// Block = GROUPS groups of D threads; each group computes R relation rows.
// MODE 0: msg -> atomicMax(enc(msg)) into mx_enc
// MODE 1: recompute msg -> atomicAdd(exp(SMOOTH*(msg - mx))) into ssum
template<int D, int R, int GROUPS, int MODE>
__global__ __launch_bounds__(D * GROUPS)
void rel_pass_kernel(const float* __restrict__ emb,
                     const int* __restrict__ idx, int nRows,
                     const float* __restrict__ wi, const float* __restrict__ bi,
                     const float* __restrict__ wo, const float* __restrict__ bo,
                     unsigned int* __restrict__ mx_enc,
                     const float* __restrict__ mx,
                     float* __restrict__ ssum) {
    __shared__ float xs[GROUPS][R][D];
    __shared__ float hs[GROUPS][R][D];
    __shared__ float wch[D][KC + 1];

    const int tid = threadIdx.x;
    const int g = tid / D;
    const int j = tid - g * D;
    const int ARITY = D / E;
    const int e = j & (E - 1);
    const int row0 = (blockIdx.x * GROUPS + g) * R;

    int objs[R];
#pragma unroll
    for (int r = 0; r < R; ++r) {
        int row = row0 + r;
        if (row < nRows) {
            int obj = idx[row * ARITY + (j >> 6)];
            objs[r] = obj;
            xs[g][r][j] = emb[(size_t)obj * E + e];
        } else {
            objs[r] = -1;
            xs[g][r][j] = 0.0f;
        }
    }

    float acc[R];
    // ---------------- layer 1: y = x @ wi.T + bi ----------------
    {
        float b = bi[j];
#pragma unroll
        for (int r = 0; r < R; ++r) acc[r] = b;
        for (int k0 = 0; k0 < D; k0 += KC) {
            __syncthreads();
            for (int i = tid; i < D * KC; i += D * GROUPS) {
                int j2 = i >> 5, kc = i & 31;
                wch[j2][kc] = wi[(size_t)j2 * D + k0 + kc];
            }
            __syncthreads();
            for (int kc = 0; kc < KC; kc += 4) {
                float w0 = wch[j][kc + 0];
                float w1 = wch[j][kc + 1];
                float w2 = wch[j][kc + 2];
                float w3 = wch[j][kc + 3];
#pragma unroll
                for (int r = 0; r < R; ++r) {
                    float4 xv = *(const float4*)&xs[g][r][k0 + kc];
                    acc[r] = fmaf(xv.x, w0, acc[r]);
                    acc[r] = fmaf(xv.y, w1, acc[r]);
                    acc[r] = fmaf(xv.z, w2, acc[r]);
                    acc[r] = fmaf(xv.w, w3, acc[r]);
                }
            }
        }
    }
    __syncthreads();
#pragma unroll
    for (int r = 0; r < R; ++r) hs[g][r][j] = mish_f(acc[r]);

    // ---------------- layer 2: y2 = h @ wo.T + bo ----------------
    {
        float b = bo[j];
#pragma unroll
        for (int r = 0; r < R; ++r) acc[r] = b;
        for (int k0 = 0; k0 < D; k0 += KC) {
            __syncthreads();
            for (int i = tid; i < D * KC; i += D * GROUPS) {
                int j2 = i >> 5, kc = i & 31;
                wch[j2][kc] = wo[(size_t)j2 * D + k0 + kc];
            }
            __syncthreads();
            for (int kc = 0; kc < KC; kc += 4) {
                float w0 = wch[j][kc + 0];
                float w1 = wch[j][kc + 1];
                float w2 = wch[j][kc + 2];
                float w3 = wch[j][kc + 3];
#pragma unroll
                for (int r = 0; r < R; ++r) {
                    float4 hv = *(const float4*)&hs[g][r][k0 + kc];
                    acc[r] = fmaf(hv.x, w0, acc[r]);
                    acc[r] = fmaf(hv.y, w1, acc[r]);
                    acc[r] = fmaf(hv.z, w2, acc[r]);
                    acc[r] = fmaf(hv.w, w3, acc[r]);
                }
            }
        }
    }

    // ---------------- scatter ----------------
#pragma unroll
    for (int r = 0; r < R; ++r) {
        if (objs[r] >= 0) {
            float m = xs[g][r][j] + acc[r];   // residual
            size_t dst = (size_t)objs[r] * E + e;
            if (MODE == 0) {
                atomicMax(&mx_enc[dst], enc_f32(m));
            } else {
                float mxv = mx[dst];
                atomicAdd(&ssum[dst], expf(SMOOTH * (m - mxv)));
            }
        }
    }
}

__global__ void mx_decode_kernel(unsigned int* __restrict__ mx, long long n) {
    long long tid = (long long)blockIdx.x * blockDim.x + threadIdx.x;
    if (tid >= n) return;
    unsigned int u = mx[tid];
    float v;
    if (u == 0u) {
        v = 0.0f;  // untouched segment sentinel (ref: -inf -> 0)
    } else {
        int b = (u & 0x80000000u) ? (int)(u & 0x7FFFFFFFu) : (int)(~u);
        v = __int_as_float(b);
    }
    ((float*)mx)[tid] = v;
}

// Update MLP: 2 groups x 128 threads, R=16 objects per group.
__global__ __launch_bounds__(256)
void update_kernel(const float* __restrict__ emb,
                   const float* __restrict__ mx,
                   const float* __restrict__ ssum,
                   const float* __restrict__ wi, const float* __restrict__ bi,
                   const float* __restrict__ wo, const float* __restrict__ bo,
                   float* __restrict__ out) {
    __shared__ float uin[2][16][128];
    __shared__ float h[2][16][128];
    __shared__ float wch[128][KC + 1];
    const int tid = threadIdx.x;
    const int g = tid >> 7;
    const int j = tid & 127;
    const int row0 = (blockIdx.x * 2 + g) * 16;

#pragma unroll
    for (int r = 0; r < 16; ++r) {
        int obj = row0 + r;
        float v = 0.0f;
        if (obj < NOBJ) {
            if (j < 64) {
                float s = ssum[(size_t)obj * 64 + j] + 1e-16f;
                v = logf(s) / SMOOTH + mx[(size_t)obj * 64 + j];
            } else {
                v = emb[(size_t)obj * 64 + (j - 64)];
            }
        }
        uin[g][r][j] = v;
    }

    float acc[16];
    // layer 1: 128 -> 128
    {
        float b = bi[j];
#pragma unroll
        for (int r = 0; r < 16; ++r) acc[r] = b;
        for (int k0 = 0; k0 < 128; k0 += KC) {
            __syncthreads();
            for (int i = tid; i < 128 * KC; i += 256) {
                int j2 = i >> 5, kc = i & 31;
                wch[j2][kc] = wi[(size_t)j2 * 128 + k0 + kc];
            }
            __syncthreads();
            for (int kc = 0; kc < KC; kc += 4) {
                float w0 = wch[j][kc + 0];
                float w1 = wch[j][kc + 1];
                float w2 = wch[j][kc + 2];
                float w3 = wch[j][kc + 3];
#pragma unroll
                for (int r = 0; r < 16; ++r) {
                    float4 xv = *(const float4*)&uin[g][r][k0 + kc];
                    acc[r] = fmaf(xv.x, w0, acc[r]);
                    acc[r] = fmaf(xv.y, w1, acc[r]);
                    acc[r] = fmaf(xv.z, w2, acc[r]);
                    acc[r] = fmaf(xv.w, w3, acc[r]);
                }
            }
        }
    }
    __syncthreads();
#pragma unroll
    for (int r = 0; r < 16; ++r) h[g][r][j] = mish_f(acc[r]);

    // layer 2: 128 -> 64 (threads j<64 produce outputs; all threads stage)
    {
        float b = (j < 64) ? bo[j] : 0.0f;
#pragma unroll
        for (int r = 0; r < 16; ++r) acc[r] = b;
        for (int k0 = 0; k0 < 128; k0 += KC) {
            __syncthreads();
            for (int i = tid; i < 64 * KC; i += 256) {
                int j2 = i >> 5, kc = i & 31;
                wch[j2][kc] = wo[(size_t)j2 * 128 + k0 + kc];
            }
            __syncthreads();
            if (j < 64) {
                for (int kc = 0; kc < KC; kc += 4) {
                    float w0 = wch[j][kc + 0];
                    float w1 = wch[j][kc + 1];
                    float w2 = wch[j][kc + 2];
                    float w3 = wch[j][kc + 3];
#pragma unroll
                    for (int r = 0; r < 16; ++r) {
                        float4 hv = *(const float4*)&h[g][r][k0 + kc];
                        acc[r] = fmaf(hv.x, w0, acc[r]);
                        acc[r] = fmaf(hv.y, w1, acc[r]);
                        acc[r] = fmaf(hv.z, w2, acc[r]);
                        acc[r] = fmaf(hv.w, w3, acc[r]);
                    }
                }
            }
        }
    }
    if (j < 64) {
#pragma unroll
        for (int r = 0; r < 16; ++r) {
            int obj = row0 + r;
            if (obj < NOBJ)
                out[(size_t)obj * 64 + j] = emb[(size_t)obj * 64 + j] + acc[r];
        }
    }
}

extern "C" void kernel_launch(void* const* d_in, const int* in_sizes, int n_in,
                              void* d_out, int out_size, void* d_ws, size_t ws_size,
                              hipStream_t stream) {
    const float* emb = (const float*)d_in[0];
    const int* iu = (const int*)d_in[1];
    const int* ib = (const int*)d_in[2];
    const int* it = (const int*)d_in[3];
    const float* uwi = (const float*)d_in[4];
    const float* ubi = (const float*)d_in[5];
    const float* uwo = (const float*)d_in[6];
    const float* ubo = (const float*)d_in[7];
    const float* bwi = (const float*)d_in[8];
    const float* bbi = (const float*)d_in[9];
    const float* bwo = (const float*)d_in[10];
    const float* bbo = (const float*)d_in[11];
    const float* twi = (const float*)d_in[12];
    const float* tbi = (const float*)d_in[13];
    const float* two = (const float*)d_in[14];
    const float* tbo = (const float*)d_in[15];
    const float* pwi = (const float*)d_in[16];
    const float* pbi = (const float*)d_in[17];
    const float* pwo = (const float*)d_in[18];
    const float* pbo = (const float*)d_in[19];

    const int nU = in_sizes[1];
    const int nB = in_sizes[2];
    const int nT = in_sizes[3];
    const int rowsU = nU;
    const int rowsB = nB / 2;
    const int rowsT = nT / 3;

    const size_t seg = (size_t)NOBJ * 64;   // 6.4M elems = 25.6 MB
    float* ws = (float*)d_ws;
    float* mx;
    float* ssum;
    if (ws_size >= 2 * seg * sizeof(float)) {
        mx = ws;
        ssum = ws + seg;
    } else {
        mx = (float*)d_out;   // fallback: max buffer lives in d_out until update
        ssum = ws;
    }

    hipMemsetAsync(mx, 0, seg * sizeof(float), stream);
    hipMemsetAsync(ssum, 0, seg * sizeof(float), stream);

    const int gU = (rowsU + 63) / 64;    // 4 groups x 16 rows
    const int gB = (rowsB + 31) / 32;    // 2 groups x 16 rows
    const int gT = (rowsT + 15) / 16;    // 1 group  x 16 rows

    // pass 1: messages -> encoded atomic max
    rel_pass_kernel<64, 16, 4, 0><<<gU, 256, 0, stream>>>(
        emb, iu, rowsU, uwi, ubi, uwo, ubo, (unsigned int*)mx, nullptr, nullptr);
    rel_pass_kernel<128, 16, 2, 0><<<gB, 256, 0, stream>>>(
        emb, ib, rowsB, bwi, bbi, bwo, bbo, (unsigned int*)mx, nullptr, nullptr);
    rel_pass_kernel<192, 16, 1, 0><<<gT, 192, 0, stream>>>(
        emb, it, rowsT, twi, tbi, two, tbo, (unsigned int*)mx, nullptr, nullptr);

    mx_decode_kernel<<<(int)((seg + 255) / 256), 256, 0, stream>>>(
        (unsigned int*)mx, (long long)seg);

    // pass 2: recompute messages -> exp-sum
    rel_pass_kernel<64, 16, 4, 1><<<gU, 256, 0, stream>>>(
        emb, iu, rowsU, uwi, ubi, uwo, ubo, nullptr, mx, ssum);
    rel_pass_kernel<128, 16, 2, 1><<<gB, 256, 0, stream>>>(
        emb, ib, rowsB, bwi, bbi, bwo, bbo, nullptr, mx, ssum);
    rel_pass_kernel<192, 16, 1, 1><<<gT, 192, 0, stream>>>(
        emb, it, rowsT, twi, tbi, two, tbo, nullptr, mx, ssum);

    // final LSE + update MLP
    update_kernel<<<(NOBJ + 31) / 32, 256, 0, stream>>>(
        emb, mx, ssum, pwi, pbi, pwo, pbo, (float*)d_out);
}

// Round 3
// 1031.584 us; speedup vs baseline: 4.2366x; 4.2366x over previous
//
#include <hip/hip_runtime.h>
#include <hip/hip_bf16.h>
#include <math.h>

#define NOBJ 100000
#define SMOOTH 12.0f

typedef __attribute__((ext_vector_type(8))) short bf16x8;
typedef __attribute__((ext_vector_type(4))) float f32x4;
typedef unsigned short u16;
typedef unsigned int u32;

// bf16 weight table (converted once per launch; every block reads it -> L1/L2 resident)
#define OFF_UWI 0
#define OFF_UWO 4096
#define OFF_BWI 8192
#define OFF_BWO 24576
#define OFF_TWI 40960
#define OFF_TWO 77824
#define OFF_PWI 114688
#define OFF_PWO 131072
#define WTOT    139264
__device__ u16 g_wbf[WTOT];

__device__ __forceinline__ u16 f2b(float x) {
    union { float f; u32 u; } v; v.f = x;
    u32 r = v.u + 0x7FFFu + ((v.u >> 16) & 1);  // RNE
    return (u16)(r >> 16);
}
__device__ __forceinline__ float b2f(u16 b) {
    union { u32 u; float f; } v; v.u = ((u32)b) << 16; return v.f;
}
__device__ __forceinline__ u32 enc_f32(float v) {
    int b = __float_as_int(v);
    return (b >= 0) ? ((u32)b | 0x80000000u) : ~((u32)b);
}
// mish(x) = x*tanh(softplus(x)) = x*(e^2+2e)/(e^2+2e+2), e=exp(x). Clamp avoids e^2 overflow.
__device__ __forceinline__ float mish_fast(float x) {
    float e = __expf(fminf(x, 15.f));
    float t = __builtin_fmaf(e, e, 2.f * e);
    return x * t * __builtin_amdgcn_rcpf(t + 2.f);
}

__global__ void conv_weights(const float* __restrict__ uwi, const float* __restrict__ uwo,
                             const float* __restrict__ bwi, const float* __restrict__ bwo,
                             const float* __restrict__ twi, const float* __restrict__ two_,
                             const float* __restrict__ pwi, const float* __restrict__ pwo) {
    int i = blockIdx.x * 256 + threadIdx.x;
    if (i >= WTOT) return;
    const float* src; int off;
    if      (i < OFF_UWO) { src = uwi; off = OFF_UWI; }
    else if (i < OFF_BWI) { src = uwo; off = OFF_UWO; }
    else if (i < OFF_BWO) { src = bwi; off = OFF_BWI; }
    else if (i < OFF_TWI) { src = bwo; off = OFF_BWO; }
    else if (i < OFF_TWO) { src = twi; off = OFF_TWI; }
    else if (i < OFF_PWI) { src = two_; off = OFF_TWO; }
    else if (i < OFF_PWO) { src = pwi; off = OFF_PWI; }
    else                  { src = pwo; off = OFF_PWO; }
    g_wbf[i] = f2b(src[i - off]);
}

// Fused relation MLP (bf16 MFMA) + scatter.
// Block = MW waves; wave w computes rows [w*16, w*16+16) of an M=MW*16 row tile, all N cols.
// MODE 0: atomicMax(enc(msg)); MODE 1: atomicAdd(exp(SMOOTH*(msg-mx))).
template<int D, int MW, int MODE, int WOFF_I, int WOFF_O>
__global__ __launch_bounds__(64 * MW)
void rel_pass_mfma(const float* __restrict__ emb,
                   const int* __restrict__ idx, int nRows,
                   const float* __restrict__ bi, const float* __restrict__ bo,
                   u32* __restrict__ mx_enc, const float* __restrict__ mx,
                   float* __restrict__ ssum) {
    constexpr int ARITY = D / 64;
    constexpr int NT = D / 16;
    constexpr int KT = D / 32;
    constexpr int M = MW * 16;
    __shared__ u16 xs[M * D];
    __shared__ u16 hs[M * D];
    __shared__ int objsm[M * ARITY];

    const int tid = threadIdx.x;
    const int w = tid >> 6, l = tid & 63;
    const int lo = l & 15, hi = l >> 4;
    const int row0 = blockIdx.x * M;

    for (int i = tid; i < M * ARITY; i += 64 * MW) {
        int row = row0 + i / ARITY;
        objsm[i] = (row < nRows) ? idx[(size_t)row * ARITY + i % ARITY] : -1;
    }
    __syncthreads();
    // gather + f32->bf16, XOR-swizzled LDS ( ^ (row&7)<<3 in ushort units = (row&7)<<4 bytes )
    for (int i = tid; i < M * D / 4; i += 64 * MW) {
        int r = i / (D / 4), c4 = i % (D / 4);
        int obj = objsm[r * ARITY + (c4 >> 4)];
        float4 v = make_float4(0.f, 0.f, 0.f, 0.f);
        if (obj >= 0) v = *(const float4*)(emb + (size_t)obj * 64 + (c4 & 15) * 4);
        int sw = (r * D + c4 * 4) ^ ((r & 7) << 3);
        ushort4 o;
        o.x = f2b(v.x); o.y = f2b(v.y); o.z = f2b(v.z); o.w = f2b(v.w);
        *(ushort4*)&xs[sw] = o;
    }
    __syncthreads();

    f32x4 acc[NT];
    const int arow = w * 16 + lo;
    const int asw = ((arow & 7) << 3);

    // ---- layer 1: y1 = x @ wi^T + bi ----
#pragma unroll
    for (int n = 0; n < NT; ++n) { float b = bi[n * 16 + lo]; acc[n] = (f32x4){b, b, b, b}; }
#pragma unroll
    for (int kk = 0; kk < KT; ++kk) {
        bf16x8 a = *(const bf16x8*)&xs[(arow * D + kk * 32 + hi * 8) ^ asw];
#pragma unroll
        for (int n = 0; n < NT; ++n) {
            bf16x8 b = *(const bf16x8*)&g_wbf[WOFF_I + (n * 16 + lo) * D + kk * 32 + hi * 8];
            acc[n] = __builtin_amdgcn_mfma_f32_16x16x32_bf16(a, b, acc[n], 0, 0, 0);
        }
    }
    // mish -> hs (each wave writes only its own 16 rows)
#pragma unroll
    for (int n = 0; n < NT; ++n) {
#pragma unroll
        for (int r = 0; r < 4; ++r) {
            int row = w * 16 + hi * 4 + r;
            int col = n * 16 + lo;
            hs[(row * D + col) ^ ((row & 7) << 3)] = f2b(mish_fast(acc[n][r]));
        }
    }
    __syncthreads();

    // ---- layer 2: y2 = h @ wo^T + bo ----
#pragma unroll
    for (int n = 0; n < NT; ++n) { float b = bo[n * 16 + lo]; acc[n] = (f32x4){b, b, b, b}; }
#pragma unroll
    for (int kk = 0; kk < KT; ++kk) {
        bf16x8 a = *(const bf16x8*)&hs[(arow * D + kk * 32 + hi * 8) ^ asw];
#pragma unroll
        for (int n = 0; n < NT; ++n) {
            bf16x8 b = *(const bf16x8*)&g_wbf[WOFF_O + (n * 16 + lo) * D + kk * 32 + hi * 8];
            acc[n] = __builtin_amdgcn_mfma_f32_16x16x32_bf16(a, b, acc[n], 0, 0, 0);
        }
    }

    // ---- residual + scatter ----
#pragma unroll
    for (int n = 0; n < NT; ++n) {
        int col = n * 16 + lo;
#pragma unroll
        for (int r = 0; r < 4; ++r) {
            int row = w * 16 + hi * 4 + r;
            int obj = objsm[row * ARITY + (col >> 6)];
            if (obj < 0) continue;
            float xv = b2f(xs[(row * D + col) ^ ((row & 7) << 3)]);
            float m = xv + acc[n][r];
            size_t dst = (size_t)obj * 64 + (col & 63);
            if (MODE == 0) {
                atomicMax(&mx_enc[dst], enc_f32(m));
            } else {
                atomicAdd(&ssum[dst], __expf(SMOOTH * (m - mx[dst])));
            }
        }
    }
}

__global__ void mx_decode_kernel(u32* __restrict__ mx, long long n) {
    long long tid = (long long)blockIdx.x * blockDim.x + threadIdx.x;
    if (tid >= n) return;
    u32 u = mx[tid];
    float v;
    if (u == 0u) v = 0.0f;  // untouched segment (ref: -inf -> 0)
    else {
        int b = (u & 0x80000000u) ? (int)(u & 0x7FFFFFFFu) : (int)(~u);
        v = __int_as_float(b);
    }
    ((float*)mx)[tid] = v;
}

// Update MLP (128->128 mish ->64) via MFMA; 64 objs/block, 4 waves.
__global__ __launch_bounds__(256)
void update_mfma(const float* __restrict__ emb,
                 const float* __restrict__ mx, const float* __restrict__ ssum,
                 const float* __restrict__ bi, const float* __restrict__ bo,
                 float* __restrict__ out) {
    __shared__ u16 uin[64 * 128];
    __shared__ u16 h[64 * 128];
    const int tid = threadIdx.x;
    const int w = tid >> 6, l = tid & 63, lo = l & 15, hi = l >> 4;
    const int row0 = blockIdx.x * 64;

    for (int i = tid; i < 64 * 128; i += 256) {
        int r = i >> 7, c = i & 127;
        int obj = row0 + r;
        float v = 0.f;
        if (obj < NOBJ) {
            if (c < 64) {
                float s = ssum[(size_t)obj * 64 + c] + 1e-16f;
                v = __logf(s) * (1.f / SMOOTH) + mx[(size_t)obj * 64 + c];
            } else v = emb[(size_t)obj * 64 + (c - 64)];
        }
        uin[i ^ ((r & 7) << 3)] = f2b(v);
    }
    __syncthreads();

    const int arow = w * 16 + lo;
    const int asw = ((arow & 7) << 3);
    f32x4 acc[8];
#pragma unroll
    for (int n = 0; n < 8; ++n) { float b = bi[n * 16 + lo]; acc[n] = (f32x4){b, b, b, b}; }
#pragma unroll
    for (int kk = 0; kk < 4; ++kk) {
        bf16x8 a = *(const bf16x8*)&uin[(arow * 128 + kk * 32 + hi * 8) ^ asw];
#pragma unroll
        for (int n = 0; n < 8; ++n) {
            bf16x8 b = *(const bf16x8*)&g_wbf[OFF_PWI + (n * 16 + lo) * 128 + kk * 32 + hi * 8];
            acc[n] = __builtin_amdgcn_mfma_f32_16x16x32_bf16(a, b, acc[n], 0, 0, 0);
        }
    }
#pragma unroll
    for (int n = 0; n < 8; ++n) {
#pragma unroll
        for (int r = 0; r < 4; ++r) {
            int row = w * 16 + hi * 4 + r;
            int col = n * 16 + lo;
            h[(row * 128 + col) ^ ((row & 7) << 3)] = f2b(mish_fast(acc[n][r]));
        }
    }
    __syncthreads();

    f32x4 acc2[4];
#pragma unroll
    for (int n = 0; n < 4; ++n) { float b = bo[n * 16 + lo]; acc2[n] = (f32x4){b, b, b, b}; }
#pragma unroll
    for (int kk = 0; kk < 4; ++kk) {
        bf16x8 a = *(const bf16x8*)&h[(arow * 128 + kk * 32 + hi * 8) ^ asw];
#pragma unroll
        for (int n = 0; n < 4; ++n) {
            bf16x8 b = *(const bf16x8*)&g_wbf[OFF_PWO + (n * 16 + lo) * 128 + kk * 32 + hi * 8];
            acc2[n] = __builtin_amdgcn_mfma_f32_16x16x32_bf16(a, b, acc2[n], 0, 0, 0);
        }
    }
#pragma unroll
    for (int n = 0; n < 4; ++n) {
        int col = n * 16 + lo;
#pragma unroll
        for (int r = 0; r < 4; ++r) {
            int row = w * 16 + hi * 4 + r;
            int obj = row0 + row;
            if (obj < NOBJ)
                out[(size_t)obj * 64 + col] = emb[(size_t)obj * 64 + col] + acc2[n][r];
        }
    }
}

extern "C" void kernel_launch(void* const* d_in, const int* in_sizes, int n_in,
                              void* d_out, int out_size, void* d_ws, size_t ws_size,
                              hipStream_t stream) {
    const float* emb = (const float*)d_in[0];
    const int* iu = (const int*)d_in[1];
    const int* ib = (const int*)d_in[2];
    const int* it = (const int*)d_in[3];
    const float* uwi = (const float*)d_in[4];
    const float* ubi = (const float*)d_in[5];
    const float* uwo = (const float*)d_in[6];
    const float* ubo = (const float*)d_in[7];
    const float* bwi = (const float*)d_in[8];
    const float* bbi = (const float*)d_in[9];
    const float* bwo = (const float*)d_in[10];
    const float* bbo = (const float*)d_in[11];
    const float* twi = (const float*)d_in[12];
    const float* tbi = (const float*)d_in[13];
    const float* two_ = (const float*)d_in[14];
    const float* tbo = (const float*)d_in[15];
    const float* pwi = (const float*)d_in[16];
    const float* pbi = (const float*)d_in[17];
    const float* pwo = (const float*)d_in[18];
    const float* pbo = (const float*)d_in[19];

    const int nU = in_sizes[1];
    const int nB = in_sizes[2];
    const int nT = in_sizes[3];
    const int rowsU = nU;
    const int rowsB = nB / 2;
    const int rowsT = nT / 3;

    const size_t seg = (size_t)NOBJ * 64;
    float* mxf;
    float* ssum;
    if (ws_size >= 2 * seg * sizeof(float)) {
        mxf = (float*)d_ws;
        ssum = (float*)d_ws + seg;
    } else {
        mxf = (float*)d_out;       // safe: update_kernel reads mx rows before writing same rows
        ssum = (float*)d_ws;
    }

    conv_weights<<<(WTOT + 255) / 256, 256, 0, stream>>>(uwi, uwo, bwi, bwo, twi, two_, pwi, pwo);
    hipMemsetAsync(mxf, 0, seg * sizeof(float), stream);
    hipMemsetAsync(ssum, 0, seg * sizeof(float), stream);

    const int gU = (rowsU + 63) / 64;
    const int gB = (rowsB + 63) / 64;
    const int gT = (rowsT + 31) / 32;

    // pass 1: msgs -> encoded atomicMax
    rel_pass_mfma<64, 4, 0, OFF_UWI, OFF_UWO><<<gU, 256, 0, stream>>>(
        emb, iu, rowsU, ubi, ubo, (u32*)mxf, nullptr, nullptr);
    rel_pass_mfma<128, 4, 0, OFF_BWI, OFF_BWO><<<gB, 256, 0, stream>>>(
        emb, ib, rowsB, bbi, bbo, (u32*)mxf, nullptr, nullptr);
    rel_pass_mfma<192, 2, 0, OFF_TWI, OFF_TWO><<<gT, 128, 0, stream>>>(
        emb, it, rowsT, tbi, tbo, (u32*)mxf, nullptr, nullptr);

    mx_decode_kernel<<<(int)((seg + 255) / 256), 256, 0, stream>>>((u32*)mxf, (long long)seg);

    // pass 2: recompute msgs -> exp-sum
    rel_pass_mfma<64, 4, 1, OFF_UWI, OFF_UWO><<<gU, 256, 0, stream>>>(
        emb, iu, rowsU, ubi, ubo, nullptr, mxf, ssum);
    rel_pass_mfma<128, 4, 1, OFF_BWI, OFF_BWO><<<gB, 256, 0, stream>>>(
        emb, ib, rowsB, bbi, bbo, nullptr, mxf, ssum);
    rel_pass_mfma<192, 2, 1, OFF_TWI, OFF_TWO><<<gT, 128, 0, stream>>>(
        emb, it, rowsT, tbi, tbo, nullptr, mxf, ssum);

    update_mfma<<<(NOBJ + 63) / 64, 256, 0, stream>>>(emb, mxf, ssum, pbi, pbo, (float*)d_out);
}

// Round 4
// 655.611 us; speedup vs baseline: 6.6662x; 1.5735x over previous
//
#include <hip/hip_runtime.h>
#include <hip/hip_bf16.h>
#include <math.h>

#define NOBJ 100000
#define SMOOTH 12.0f

typedef __attribute__((ext_vector_type(8))) short bf16x8;
typedef __attribute__((ext_vector_type(4))) float f32x4;
typedef unsigned short u16;
typedef unsigned int u32;
typedef unsigned long long u64;

// bf16 weight table (converted once per launch; L1/L2 resident)
#define OFF_UWI 0
#define OFF_UWO 4096
#define OFF_BWI 8192
#define OFF_BWO 24576
#define OFF_TWI 40960
#define OFF_TWO 77824
#define OFF_PWI 114688
#define OFF_PWO 131072
#define WTOT    139264
__device__ u16 g_wbf[WTOT];

__device__ __forceinline__ u16 f2b(float x) {
    union { float f; u32 u; } v; v.f = x;
    u32 r = v.u + 0x7FFFu + ((v.u >> 16) & 1);  // RNE
    return (u16)(r >> 16);
}
__device__ __forceinline__ float b2f(u16 b) {
    union { u32 u; float f; } v; v.u = ((u32)b) << 16; return v.f;
}
__device__ __forceinline__ u32 enc_f32(float v) {
    int b = __float_as_int(v);
    return (b >= 0) ? ((u32)b | 0x80000000u) : ~((u32)b);
}
// mish(x) = x*(e^2+2e)/(e^2+2e+2), e=exp(x). Clamp avoids e^2 overflow.
__device__ __forceinline__ float mish_fast(float x) {
    float e = __expf(fminf(x, 15.f));
    float t = __builtin_fmaf(e, e, 2.f * e);
    return x * t * __builtin_amdgcn_rcpf(t + 2.f);
}
// exp(SMOOTH*m) as f64, no overflow/underflow for |m| <= ~50
__device__ __forceinline__ double exp12_f64(float m) {
    float t = m * (SMOOTH * 1.4426950408889634f);  // 12*log2(e)
    float n = floorf(t);
    float r = t - n;
    float f = exp2f(r);            // v_exp_f32, r in [0,1)
    return ldexp((double)f, (int)n);  // v_ldexp_f64
}
// log(S)/SMOOTH for normal-range positive double S
__device__ __forceinline__ float lse_from_sum(double S) {
    if (S == 0.0) return -3.0701134573253942f;  // log(1e-16)/12 (untouched segment)
    union { double d; u64 u; } vu; vu.d = S;
    int k = (int)((vu.u >> 52) & 0x7FF) - 1022;
    vu.u = (vu.u & 0x000FFFFFFFFFFFFFULL) | 0x3FE0000000000000ULL;  // [0.5,1)
    float fr = (float)vu.d;
    return ((float)k + __log2f(fr)) * 0.057762265046662105f;  // *ln2/12
}

__global__ void conv_weights(const float* __restrict__ uwi, const float* __restrict__ uwo,
                             const float* __restrict__ bwi, const float* __restrict__ bwo,
                             const float* __restrict__ twi, const float* __restrict__ two_,
                             const float* __restrict__ pwi, const float* __restrict__ pwo) {
    int i = blockIdx.x * 256 + threadIdx.x;
    if (i >= WTOT) return;
    const float* src; int off;
    if      (i < OFF_UWO) { src = uwi; off = OFF_UWI; }
    else if (i < OFF_BWI) { src = uwo; off = OFF_UWO; }
    else if (i < OFF_BWO) { src = bwi; off = OFF_BWI; }
    else if (i < OFF_TWI) { src = bwo; off = OFF_BWO; }
    else if (i < OFF_TWO) { src = twi; off = OFF_TWI; }
    else if (i < OFF_PWI) { src = two_; off = OFF_TWO; }
    else if (i < OFF_PWO) { src = pwi; off = OFF_PWI; }
    else                  { src = pwo; off = OFF_PWO; }
    g_wbf[i] = f2b(src[i - off]);
}

// Fused relation MLP (bf16 MFMA) + scatter.
// MODE 0: atomicMax(enc(msg)) -> mx_enc        (fallback path)
// MODE 1: atomicAdd f32 exp(12*(m-mx)) -> ssum (fallback path)
// MODE 2: f64 atomicAdd exp(12*m) -> ssum64    (single-pass path)
template<int D, int MW, int MODE, int WOFF_I, int WOFF_O>
__global__ __launch_bounds__(64 * MW)
void rel_pass_mfma(const float* __restrict__ emb,
                   const int* __restrict__ idx, int nRows,
                   const float* __restrict__ bi, const float* __restrict__ bo,
                   u32* __restrict__ mx_enc, const float* __restrict__ mx,
                   float* __restrict__ ssum, double* __restrict__ ssum64) {
    constexpr int ARITY = D / 64;
    constexpr int NT = D / 16;
    constexpr int KT = D / 32;
    constexpr int M = MW * 16;
    __shared__ u16 xs[M * D];
    __shared__ u16 hs[M * D];
    __shared__ int objsm[M * ARITY];

    const int tid = threadIdx.x;
    const int w = tid >> 6, l = tid & 63;
    const int lo = l & 15, hi = l >> 4;
    const int row0 = blockIdx.x * M;

    for (int i = tid; i < M * ARITY; i += 64 * MW) {
        int row = row0 + i / ARITY;
        objsm[i] = (row < nRows) ? idx[(size_t)row * ARITY + i % ARITY] : -1;
    }
    __syncthreads();
    // gather + f32->bf16, XOR-swizzled LDS
    for (int i = tid; i < M * D / 4; i += 64 * MW) {
        int r = i / (D / 4), c4 = i % (D / 4);
        int obj = objsm[r * ARITY + (c4 >> 4)];
        float4 v = make_float4(0.f, 0.f, 0.f, 0.f);
        if (obj >= 0) v = *(const float4*)(emb + (size_t)obj * 64 + (c4 & 15) * 4);
        int sw = (r * D + c4 * 4) ^ ((r & 7) << 3);
        ushort4 o;
        o.x = f2b(v.x); o.y = f2b(v.y); o.z = f2b(v.z); o.w = f2b(v.w);
        *(ushort4*)&xs[sw] = o;
    }
    __syncthreads();

    f32x4 acc[NT];
    const int arow = w * 16 + lo;
    const int asw = ((arow & 7) << 3);

    // ---- layer 1 ----
#pragma unroll
    for (int n = 0; n < NT; ++n) { float b = bi[n * 16 + lo]; acc[n] = (f32x4){b, b, b, b}; }
#pragma unroll
    for (int kk = 0; kk < KT; ++kk) {
        bf16x8 a = *(const bf16x8*)&xs[(arow * D + kk * 32 + hi * 8) ^ asw];
#pragma unroll
        for (int n = 0; n < NT; ++n) {
            bf16x8 b = *(const bf16x8*)&g_wbf[WOFF_I + (n * 16 + lo) * D + kk * 32 + hi * 8];
            acc[n] = __builtin_amdgcn_mfma_f32_16x16x32_bf16(a, b, acc[n], 0, 0, 0);
        }
    }
#pragma unroll
    for (int n = 0; n < NT; ++n) {
#pragma unroll
        for (int r = 0; r < 4; ++r) {
            int row = w * 16 + hi * 4 + r;
            int col = n * 16 + lo;
            hs[(row * D + col) ^ ((row & 7) << 3)] = f2b(mish_fast(acc[n][r]));
        }
    }
    __syncthreads();

    // ---- layer 2 ----
#pragma unroll
    for (int n = 0; n < NT; ++n) { float b = bo[n * 16 + lo]; acc[n] = (f32x4){b, b, b, b}; }
#pragma unroll
    for (int kk = 0; kk < KT; ++kk) {
        bf16x8 a = *(const bf16x8*)&hs[(arow * D + kk * 32 + hi * 8) ^ asw];
#pragma unroll
        for (int n = 0; n < NT; ++n) {
            bf16x8 b = *(const bf16x8*)&g_wbf[WOFF_O + (n * 16 + lo) * D + kk * 32 + hi * 8];
            acc[n] = __builtin_amdgcn_mfma_f32_16x16x32_bf16(a, b, acc[n], 0, 0, 0);
        }
    }

    // ---- residual + scatter ----
#pragma unroll
    for (int n = 0; n < NT; ++n) {
        int col = n * 16 + lo;
#pragma unroll
        for (int r = 0; r < 4; ++r) {
            int row = w * 16 + hi * 4 + r;
            int obj = objsm[row * ARITY + (col >> 6)];
            if (obj < 0) continue;
            float xv = b2f(xs[(row * D + col) ^ ((row & 7) << 3)]);
            float m = xv + acc[n][r];
            size_t dst = (size_t)obj * 64 + (col & 63);
            if (MODE == 0) {
                atomicMax(&mx_enc[dst], enc_f32(m));
            } else if (MODE == 1) {
                atomicAdd(&ssum[dst], __expf(SMOOTH * (m - mx[dst])));
            } else {
                unsafeAtomicAdd(&ssum64[dst], exp12_f64(m));
            }
        }
    }
}

__global__ void mx_decode_kernel(u32* __restrict__ mx, long long n) {
    long long tid = (long long)blockIdx.x * blockDim.x + threadIdx.x;
    if (tid >= n) return;
    u32 u = mx[tid];
    float v;
    if (u == 0u) v = 0.0f;
    else {
        int b = (u & 0x80000000u) ? (int)(u & 0x7FFFFFFFu) : (int)(~u);
        v = __int_as_float(b);
    }
    ((float*)mx)[tid] = v;
}

// Update MLP via MFMA; 64 objs/block, 4 waves. P64: read f64 single-pass sums.
template<int P64>
__global__ __launch_bounds__(256)
void update_mfma(const float* __restrict__ emb,
                 const float* __restrict__ mx, const float* __restrict__ ssum,
                 const double* __restrict__ ssum64,
                 const float* __restrict__ bi, const float* __restrict__ bo,
                 float* __restrict__ out) {
    __shared__ u16 uin[64 * 128];
    __shared__ u16 h[64 * 128];
    const int tid = threadIdx.x;
    const int w = tid >> 6, l = tid & 63, lo = l & 15, hi = l >> 4;
    const int row0 = blockIdx.x * 64;

    for (int i = tid; i < 64 * 128; i += 256) {
        int r = i >> 7, c = i & 127;
        int obj = row0 + r;
        float v = 0.f;
        if (obj < NOBJ) {
            if (c < 64) {
                if (P64) {
                    v = lse_from_sum(ssum64[(size_t)obj * 64 + c]);
                } else {
                    float s = ssum[(size_t)obj * 64 + c] + 1e-16f;
                    v = __logf(s) * (1.f / SMOOTH) + mx[(size_t)obj * 64 + c];
                }
            } else v = emb[(size_t)obj * 64 + (c - 64)];
        }
        uin[i ^ ((r & 7) << 3)] = f2b(v);
    }
    __syncthreads();

    const int arow = w * 16 + lo;
    const int asw = ((arow & 7) << 3);
    f32x4 acc[8];
#pragma unroll
    for (int n = 0; n < 8; ++n) { float b = bi[n * 16 + lo]; acc[n] = (f32x4){b, b, b, b}; }
#pragma unroll
    for (int kk = 0; kk < 4; ++kk) {
        bf16x8 a = *(const bf16x8*)&uin[(arow * 128 + kk * 32 + hi * 8) ^ asw];
#pragma unroll
        for (int n = 0; n < 8; ++n) {
            bf16x8 b = *(const bf16x8*)&g_wbf[OFF_PWI + (n * 16 + lo) * 128 + kk * 32 + hi * 8];
            acc[n] = __builtin_amdgcn_mfma_f32_16x16x32_bf16(a, b, acc[n], 0, 0, 0);
        }
    }
#pragma unroll
    for (int n = 0; n < 8; ++n) {
#pragma unroll
        for (int r = 0; r < 4; ++r) {
            int row = w * 16 + hi * 4 + r;
            int col = n * 16 + lo;
            h[(row * 128 + col) ^ ((row & 7) << 3)] = f2b(mish_fast(acc[n][r]));
        }
    }
    __syncthreads();

    f32x4 acc2[4];
#pragma unroll
    for (int n = 0; n < 4; ++n) { float b = bo[n * 16 + lo]; acc2[n] = (f32x4){b, b, b, b}; }
#pragma unroll
    for (int kk = 0; kk < 4; ++kk) {
        bf16x8 a = *(const bf16x8*)&h[(arow * 128 + kk * 32 + hi * 8) ^ asw];
#pragma unroll
        for (int n = 0; n < 4; ++n) {
            bf16x8 b = *(const bf16x8*)&g_wbf[OFF_PWO + (n * 16 + lo) * 128 + kk * 32 + hi * 8];
            acc2[n] = __builtin_amdgcn_mfma_f32_16x16x32_bf16(a, b, acc2[n], 0, 0, 0);
        }
    }
#pragma unroll
    for (int n = 0; n < 4; ++n) {
        int col = n * 16 + lo;
#pragma unroll
        for (int r = 0; r < 4; ++r) {
            int row = w * 16 + hi * 4 + r;
            int obj = row0 + row;
            if (obj < NOBJ)
                out[(size_t)obj * 64 + col] = emb[(size_t)obj * 64 + col] + acc2[n][r];
        }
    }
}

extern "C" void kernel_launch(void* const* d_in, const int* in_sizes, int n_in,
                              void* d_out, int out_size, void* d_ws, size_t ws_size,
                              hipStream_t stream) {
    const float* emb = (const float*)d_in[0];
    const int* iu = (const int*)d_in[1];
    const int* ib = (const int*)d_in[2];
    const int* it = (const int*)d_in[3];
    const float* uwi = (const float*)d_in[4];
    const float* ubi = (const float*)d_in[5];
    const float* uwo = (const float*)d_in[6];
    const float* ubo = (const float*)d_in[7];
    const float* bwi = (const float*)d_in[8];
    const float* bbi = (const float*)d_in[9];
    const float* bwo = (const float*)d_in[10];
    const float* bbo = (const float*)d_in[11];
    const float* twi = (const float*)d_in[12];
    const float* tbi = (const float*)d_in[13];
    const float* two_ = (const float*)d_in[14];
    const float* tbo = (const float*)d_in[15];
    const float* pwi = (const float*)d_in[16];
    const float* pbi = (const float*)d_in[17];
    const float* pwo = (const float*)d_in[18];
    const float* pbo = (const float*)d_in[19];

    const int nU = in_sizes[1];
    const int nB = in_sizes[2];
    const int nT = in_sizes[3];
    const int rowsU = nU;
    const int rowsB = nB / 2;
    const int rowsT = nT / 3;

    const size_t seg = (size_t)NOBJ * 64;
    const int gU = (rowsU + 63) / 64;
    const int gB = (rowsB + 63) / 64;
    const int gT = (rowsT + 31) / 32;

    conv_weights<<<(WTOT + 255) / 256, 256, 0, stream>>>(uwi, uwo, bwi, bwo, twi, two_, pwi, pwo);

    if (ws_size >= seg * sizeof(double)) {
        // ---- single-pass f64 path: exp-sum only, max cancels analytically ----
        double* ssum64 = (double*)d_ws;
        hipMemsetAsync(ssum64, 0, seg * sizeof(double), stream);

        rel_pass_mfma<64, 4, 2, OFF_UWI, OFF_UWO><<<gU, 256, 0, stream>>>(
            emb, iu, rowsU, ubi, ubo, nullptr, nullptr, nullptr, ssum64);
        rel_pass_mfma<128, 4, 2, OFF_BWI, OFF_BWO><<<gB, 256, 0, stream>>>(
            emb, ib, rowsB, bbi, bbo, nullptr, nullptr, nullptr, ssum64);
        rel_pass_mfma<192, 2, 2, OFF_TWI, OFF_TWO><<<gT, 128, 0, stream>>>(
            emb, it, rowsT, tbi, tbo, nullptr, nullptr, nullptr, ssum64);

        update_mfma<1><<<(NOBJ + 63) / 64, 256, 0, stream>>>(
            emb, nullptr, nullptr, ssum64, pbi, pbo, (float*)d_out);
    } else {
        // ---- fallback: proven two-pass f32 path ----
        float* mxf;
        float* ssum;
        if (ws_size >= 2 * seg * sizeof(float)) {
            mxf = (float*)d_ws;
            ssum = (float*)d_ws + seg;
        } else {
            mxf = (float*)d_out;
            ssum = (float*)d_ws;
        }
        hipMemsetAsync(mxf, 0, seg * sizeof(float), stream);
        hipMemsetAsync(ssum, 0, seg * sizeof(float), stream);

        rel_pass_mfma<64, 4, 0, OFF_UWI, OFF_UWO><<<gU, 256, 0, stream>>>(
            emb, iu, rowsU, ubi, ubo, (u32*)mxf, nullptr, nullptr, nullptr);
        rel_pass_mfma<128, 4, 0, OFF_BWI, OFF_BWO><<<gB, 256, 0, stream>>>(
            emb, ib, rowsB, bbi, bbo, (u32*)mxf, nullptr, nullptr, nullptr);
        rel_pass_mfma<192, 2, 0, OFF_TWI, OFF_TWO><<<gT, 128, 0, stream>>>(
            emb, it, rowsT, tbi, tbo, (u32*)mxf, nullptr, nullptr, nullptr);

        mx_decode_kernel<<<(int)((seg + 255) / 256), 256, 0, stream>>>((u32*)mxf, (long long)seg);

        rel_pass_mfma<64, 4, 1, OFF_UWI, OFF_UWO><<<gU, 256, 0, stream>>>(
            emb, iu, rowsU, ubi, ubo, nullptr, mxf, ssum, nullptr);
        rel_pass_mfma<128, 4, 1, OFF_BWI, OFF_BWO><<<gB, 256, 0, stream>>>(
            emb, ib, rowsB, bbi, bbo, nullptr, mxf, ssum, nullptr);
        rel_pass_mfma<192, 2, 1, OFF_TWI, OFF_TWO><<<gT, 128, 0, stream>>>(
            emb, it, rowsT, tbi, tbo, nullptr, mxf, ssum, nullptr);

        update_mfma<0><<<(NOBJ + 63) / 64, 256, 0, stream>>>(
            emb, mxf, ssum, nullptr, pbi, pbo, (float*)d_out);
    }
}